// Round 13
// baseline (397.475 us; speedup 1.0000x reference)
//
#include <hip/hip_runtime.h>
#include <hip/hip_bf16.h>

// ---------------------------------------------------------------------------
// MultiHopGATv2, fused formulation v11.
//   Node pass processes FOUR edges per iteration (4 independent row gathers
//   in flight per wave). Tail (deg&1 single, deg&2 pair) first -> inits m,
//   quad loop runs deferred-max fast path. fp16 xl/xr, dot2 logits.
//   L1/L2 GEMMs: split-precision bf16 MFMA. CSR: 5 dispatches.
// ---------------------------------------------------------------------------

typedef __attribute__((ext_vector_type(8))) short bf16x8;
typedef __attribute__((ext_vector_type(4))) float f32x4;
typedef _Float16 f16;
typedef __attribute__((ext_vector_type(2))) _Float16 h2;
typedef __attribute__((ext_vector_type(2))) float f2;

__device__ __forceinline__ unsigned short f2bf(float v) {
    unsigned u = __float_as_uint(v);
    u = (u + 0x7fff + ((u >> 16) & 1)) >> 16;   // round-to-nearest-even
    return (unsigned short)u;
}
__device__ __forceinline__ float bf2f(unsigned short h) {
    return __uint_as_float((unsigned)h << 16);
}

// ---------------- CSR build ----------------

__global__ void zero_int_k(int* p, int n) {
    int i = blockIdx.x * 256 + threadIdx.x;
    if (i < n) p[i] = 0;
}

__global__ void count_k(const int* __restrict__ dst, int* __restrict__ cnt,
                        int E, int EP) {
    int e = blockIdx.x * 256 + threadIdx.x;
    if (e >= EP) return;
    int d = (e < E) ? dst[e] : (e - E);
    atomicAdd(&cnt[d], 1);
}

__global__ void scan1_k(const int* __restrict__ cnt, int* __restrict__ offs,
                        int* __restrict__ partial, int N) {
    __shared__ int buf[2][1024];
    int g = blockIdx.x * 1024 + threadIdx.x;
    int v = (g < N) ? cnt[g] : 0;
    int pi = 0;
    buf[0][threadIdx.x] = v;
    __syncthreads();
    for (int s = 1; s < 1024; s <<= 1) {
        int t = buf[pi][threadIdx.x];
        if ((int)threadIdx.x >= s) t += buf[pi][threadIdx.x - s];
        buf[pi ^ 1][threadIdx.x] = t;
        pi ^= 1;
        __syncthreads();
    }
    int incl = buf[pi][threadIdx.x];
    if (g < N) offs[g + 1] = incl;
    if (threadIdx.x == 1023) partial[blockIdx.x] = incl;
}

__global__ void scan23_k(int* __restrict__ offs, const int* __restrict__ partial, int N) {
    __shared__ int preS;
    int b = blockIdx.x;
    if (threadIdx.x < 64) {
        int t = threadIdx.x;
        int v = (t < b) ? partial[t] : 0;
#pragma unroll
        for (int o = 32; o > 0; o >>= 1) v += __shfl_xor(v, o, 64);
        if (t == 0) preS = v;
    }
    __syncthreads();
    int pre = preS;
    int g = b * 1024 + threadIdx.x;
    if (g < N) offs[g + 1] += pre;
    if (g == 0) offs[0] = 0;
}

__global__ void fill2_k(const int* __restrict__ src, const int* __restrict__ dst,
                        const int* __restrict__ offs, int* __restrict__ cnt2,
                        int* __restrict__ csrc, int E, int EP) {
    int e = blockIdx.x * 256 + threadIdx.x;
    if (e >= EP) return;
    int sv, d;
    if (e < E) { sv = src[e]; d = dst[e]; }
    else       { sv = e - E;  d = sv; }
    int p = offs[d] + atomicAdd(&cnt2[d], 1);
    csrc[p] = sv;
}

// ---------------- L0 vector gemm (FIN=9), fp16 out ----------------
template <int FIN>
__global__ void gemm2_f16_k(const float* __restrict__ X,
                            const float* __restrict__ Wl, const float* __restrict__ bl,
                            const float* __restrict__ Wr, const float* __restrict__ br,
                            unsigned short* __restrict__ xl, unsigned short* __restrict__ xr,
                            int N, int HCT) {
    constexpr int RPT = 16;
    __shared__ float Xs[RPT][FIN];
    int tid  = threadIdx.x;
    int col  = blockIdx.y * 256 + tid;
    int row0 = blockIdx.x * RPT;
    for (int i = tid; i < RPT * FIN; i += 256) {
        int r = i / FIN, k = i % FIN;
        int gr = row0 + r;
        Xs[r][k] = (gr < N) ? X[(size_t)gr * FIN + k] : 0.f;
    }
    __syncthreads();
    float aL[RPT], aR[RPT];
    float b1 = bl[col], b2 = br[col];
#pragma unroll
    for (int r = 0; r < RPT; r++) { aL[r] = b1; aR[r] = b2; }
    for (int k = 0; k < FIN; k++) {
        float wl = Wl[(size_t)k * HCT + col];
        float wr = Wr[(size_t)k * HCT + col];
#pragma unroll
        for (int r = 0; r < RPT; r++) {
            float xv = Xs[r][k];
            aL[r] = fmaf(xv, wl, aL[r]);
            aR[r] = fmaf(xv, wr, aR[r]);
        }
    }
#pragma unroll
    for (int r = 0; r < RPT; r++) {
        int gr = row0 + r;
        if (gr < N) {
            xl[(size_t)gr * HCT + col] = __builtin_bit_cast(unsigned short, (f16)aL[r]);
            xr[(size_t)gr * HCT + col] = __builtin_bit_cast(unsigned short, (f16)aR[r]);
        }
    }
}

// ---------------- pack W (L1 and L2) into MFMA B-frag order, hi/lo ----------
__device__ __forceinline__ void pack_one(const float* Wl, const float* Wr,
                                         unsigned short* Wh, unsigned short* Wlo,
                                         int HCT, int t) {
    int j  = t & 7;
    int l  = (t >> 3) & 63;
    int ks = (t >> 9) & 1;
    int ct = t >> 10;
    int k  = ks * 32 + (l >> 4) * 8 + j;
    int cg = ct * 16 + (l & 15);
    float v = (cg < HCT) ? Wl[(size_t)k * HCT + cg] : Wr[(size_t)k * HCT + (cg - HCT)];
    unsigned short hi = f2bf(v);
    Wh[t]  = hi;
    Wlo[t] = f2bf(v - bf2f(hi));
}

__global__ void split_w2_k(const float* __restrict__ Wl1, const float* __restrict__ Wr1,
                           unsigned short* __restrict__ W1h, unsigned short* __restrict__ W1l,
                           const float* __restrict__ Wl2, const float* __restrict__ Wr2,
                           unsigned short* __restrict__ W2h, unsigned short* __restrict__ W2l) {
    int tid = blockIdx.x * 256 + threadIdx.x;
    if (tid < 32 * 1024) pack_one(Wl1, Wr1, W1h, W1l, 256, tid);
    else                 pack_one(Wl2, Wr2, W2h, W2l, 512, tid - 32 * 1024);
}

// ---------------- MFMA gemm: [N x 64] @ [64 x HCT] x2 -> fp16 ----------------
template <int CHUNKS>
__global__ void mfma_gemm_k(const unsigned short* __restrict__ Ahi,
                            const unsigned short* __restrict__ Alo,
                            const unsigned short* __restrict__ Wphi,
                            const unsigned short* __restrict__ Wplo,
                            const float* __restrict__ bl, const float* __restrict__ br,
                            unsigned short* __restrict__ xl, unsigned short* __restrict__ xr,
                            int N, int HCT) {
    __shared__ float lds[4][16][128];
    int tid = threadIdx.x;
    int w   = tid >> 6, l = tid & 63;
    int l15 = l & 15,  seg = l >> 4;
    int row  = blockIdx.x * 64 + w * 16 + l15;
    int arow = (row < N) ? row : (N - 1);

    bf16x8 a0h = *(const bf16x8*)(Ahi + (size_t)arow * 64 + seg * 8);
    bf16x8 a1h = *(const bf16x8*)(Ahi + (size_t)arow * 64 + 32 + seg * 8);
    bf16x8 a0l = *(const bf16x8*)(Alo + (size_t)arow * 64 + seg * 8);
    bf16x8 a1l = *(const bf16x8*)(Alo + (size_t)arow * 64 + 32 + seg * 8);

    for (int c = 0; c < CHUNKS; c++) {
        int mat   = (c * 128) / HCT;
        int mcol0 = (c * 128) % HCT;
        const float* bias = mat ? br : bl;
        unsigned short* out = mat ? xr : xl;
        f32x4 acc[8];
#pragma unroll
        for (int t = 0; t < 8; t++) {
            float bv = bias[mcol0 + t * 16 + l15];
            acc[t] = (f32x4){bv, bv, bv, bv};
        }
#pragma unroll
        for (int t = 0; t < 8; t++) {
            size_t ct = (size_t)(c * 8 + t);
            bf16x8 b0h = *(const bf16x8*)(Wphi + ((ct * 2    ) * 64 + l) * 8);
            bf16x8 b1h = *(const bf16x8*)(Wphi + ((ct * 2 + 1) * 64 + l) * 8);
            bf16x8 b0l = *(const bf16x8*)(Wplo + ((ct * 2    ) * 64 + l) * 8);
            bf16x8 b1l = *(const bf16x8*)(Wplo + ((ct * 2 + 1) * 64 + l) * 8);
            acc[t] = __builtin_amdgcn_mfma_f32_16x16x32_bf16(a0h, b0h, acc[t], 0, 0, 0);
            acc[t] = __builtin_amdgcn_mfma_f32_16x16x32_bf16(a1h, b1h, acc[t], 0, 0, 0);
            acc[t] = __builtin_amdgcn_mfma_f32_16x16x32_bf16(a0l, b0h, acc[t], 0, 0, 0);
            acc[t] = __builtin_amdgcn_mfma_f32_16x16x32_bf16(a1l, b1h, acc[t], 0, 0, 0);
            acc[t] = __builtin_amdgcn_mfma_f32_16x16x32_bf16(a0h, b0l, acc[t], 0, 0, 0);
            acc[t] = __builtin_amdgcn_mfma_f32_16x16x32_bf16(a1h, b1l, acc[t], 0, 0, 0);
        }
#pragma unroll
        for (int t = 0; t < 8; t++)
#pragma unroll
            for (int r = 0; r < 4; r++)
                lds[w][seg * 4 + r][t * 16 + l15] = acc[t][r];
#pragma unroll
        for (int r = 0; r < 16; r++) {
            int orow = blockIdx.x * 64 + w * 16 + r;
            if (orow < N) {
                float v0 = lds[w][r][2 * l];
                float v1 = lds[w][r][2 * l + 1];
                h2 hv = { (f16)v0, (f16)v1 };
                *(unsigned*)(out + (size_t)orow * HCT + mcol0 + 2 * l) =
                    __builtin_bit_cast(unsigned, hv);
            }
        }
    }
}

// ---------------- node pass helpers ----------------

template <int NW>
__device__ __forceinline__ float edge_logit(const unsigned* rr, const h2* xrh,
                                            const h2* ath, h2* a) {
    float p1 = 0.f, p2 = 0.f;
#pragma unroll
    for (int i = 0; i < NW; i++) {
        h2 xv = __builtin_bit_cast(h2, rr[i]);
        a[i] = xv + xrh[i];
        unsigned au = __builtin_bit_cast(unsigned, a[i]) & 0x7FFF7FFFu;
        p1 = __builtin_amdgcn_fdot2(ath[i], a[i], p1, false);
        p2 = __builtin_amdgcn_fdot2(ath[i], __builtin_bit_cast(h2, au), p2, false);
    }
    return fmaf(0.6f, p1, 0.4f * p2);
}

__device__ __forceinline__ float head_reduce(float p) {
    p += __shfl_xor(p, 1, 64);
    p += __shfl_xor(p, 2, 64);
    p += __shfl_xor(p, 4, 64);
    p += __shfl_xor(p, 8, 64);
    return p;
}

template <int NW>
__device__ __forceinline__ void exact_update(float p, const h2* a,
                                             float& m, float& s, f2* acc) {
    float nm = fmaxf(m, p);
    float r  = __expf(m - nm);
    float w  = __expf(p - nm);
    s = fmaf(s, r, w);
    f2 r2 = {r, r}, w2 = {w, w};
#pragma unroll
    for (int i = 0; i < NW; i++) {
        f2 af = __builtin_convertvector(a[i], f2);
        acc[i] = __builtin_elementwise_fma(acc[i], r2, af * w2);
    }
    m = nm;
}

template <int NW>
__device__ __forceinline__ void fast_update(float w, const h2* a, f2* acc) {
    f2 w2 = {w, w};
#pragma unroll
    for (int i = 0; i < NW; i++) {
        f2 af = __builtin_convertvector(a[i], f2);
        acc[i] = __builtin_elementwise_fma(af, w2, acc[i]);
    }
}

// ---------------- fused node pass: 4 edges per iteration ----------------
// OUT=0: write relu(res) as hi/lo bf16 split; OUT=1: fp32 out (no relu).
// acc accumulates w*a (a = xv+xr); epilogue: out = acc/s - xr per head.
template <int F, int OUT>
__global__ void node_fused_k(const unsigned short* __restrict__ xl,
                             const unsigned short* __restrict__ xr,
                             const float* __restrict__ att, const float* __restrict__ bias,
                             const int* __restrict__ offs, const int* __restrict__ csrc,
                             unsigned short* __restrict__ Yhi, unsigned short* __restrict__ Ylo,
                             float* __restrict__ out, int N) {
    constexpr int HCT = 64 * F;
    constexpr int NW  = F / 2;
    int wv   = blockIdx.x * 4 + (threadIdx.x >> 6);
    int lane = threadIdx.x & 63;
    if (wv >= N) return;

    h2 xrh[NW], ath[NW];
    {
        const unsigned* xp = (const unsigned*)(xr + (size_t)wv * HCT + lane * F);
#pragma unroll
        for (int i = 0; i < NW; i++) {
            xrh[i] = __builtin_bit_cast(h2, xp[i]);
            ath[i] = h2{ (f16)att[lane * F + 2 * i], (f16)att[lane * F + 2 * i + 1] };
        }
    }

    int o0 = offs[wv], o1 = offs[wv + 1];
    int deg = o1 - o0;
    float m = -1e30f, s = 0.f;
    f2 acc[NW];
#pragma unroll
    for (int i = 0; i < NW; i++) acc[i] = f2{0.f, 0.f};

    int j = o0;
    if (deg & 1) {                          // single (exact) — also inits m
        const unsigned* xp = (const unsigned*)(xl + (size_t)csrc[j] * HCT + lane * F);
        unsigned rr[NW];
#pragma unroll
        for (int i = 0; i < NW; i++) rr[i] = xp[i];
        h2 a[NW];
        float p = head_reduce(edge_logit<NW>(rr, xrh, ath, a));
        exact_update<NW>(p, a, m, s, acc);
        j++;
    }
    if (deg & 2) {                          // pair
        const unsigned* xp0 = (const unsigned*)(xl + (size_t)csrc[j]     * HCT + lane * F);
        const unsigned* xp1 = (const unsigned*)(xl + (size_t)csrc[j + 1] * HCT + lane * F);
        unsigned r0[NW], r1[NW];
#pragma unroll
        for (int i = 0; i < NW; i++) r0[i] = xp0[i];
#pragma unroll
        for (int i = 0; i < NW; i++) r1[i] = xp1[i];
        h2 a0[NW], a1[NW];
        float pa = edge_logit<NW>(r0, xrh, ath, a0);
        float pb = edge_logit<NW>(r1, xrh, ath, a1);
        pa = head_reduce(pa);
        pb = head_reduce(pb);
        if (__any(fmaxf(pa, pb) > m + 20.f)) {
            exact_update<NW>(pa, a0, m, s, acc);
            exact_update<NW>(pb, a1, m, s, acc);
        } else {
            float wa = __expf(pa - m), wb = __expf(pb - m);
            s += wa + wb;
            fast_update<NW>(wa, a0, acc);
            fast_update<NW>(wb, a1, acc);
        }
        j += 2;
    }
    for (; j < o1; j += 4) {                // quad loop: 4 gathers in flight
        const unsigned* xp0 = (const unsigned*)(xl + (size_t)csrc[j]     * HCT + lane * F);
        const unsigned* xp1 = (const unsigned*)(xl + (size_t)csrc[j + 1] * HCT + lane * F);
        const unsigned* xp2 = (const unsigned*)(xl + (size_t)csrc[j + 2] * HCT + lane * F);
        const unsigned* xp3 = (const unsigned*)(xl + (size_t)csrc[j + 3] * HCT + lane * F);
        unsigned r0[NW], r1[NW], r2[NW], r3[NW];
#pragma unroll
        for (int i = 0; i < NW; i++) r0[i] = xp0[i];
#pragma unroll
        for (int i = 0; i < NW; i++) r1[i] = xp1[i];
#pragma unroll
        for (int i = 0; i < NW; i++) r2[i] = xp2[i];
#pragma unroll
        for (int i = 0; i < NW; i++) r3[i] = xp3[i];
        h2 a0[NW], a1[NW], a2[NW], a3[NW];
        float pa = edge_logit<NW>(r0, xrh, ath, a0);
        float pb = edge_logit<NW>(r1, xrh, ath, a1);
        float pc = edge_logit<NW>(r2, xrh, ath, a2);
        float pd = edge_logit<NW>(r3, xrh, ath, a3);
        pa = head_reduce(pa);
        pb = head_reduce(pb);
        pc = head_reduce(pc);
        pd = head_reduce(pd);
        float pm = fmaxf(fmaxf(pa, pb), fmaxf(pc, pd));
        if (__any(pm > m + 20.f)) {          // rare: exact sequential
            exact_update<NW>(pa, a0, m, s, acc);
            exact_update<NW>(pb, a1, m, s, acc);
            exact_update<NW>(pc, a2, m, s, acc);
            exact_update<NW>(pd, a3, m, s, acc);
        } else {                              // common: all <= m+20
            float wa = __expf(pa - m), wb = __expf(pb - m);
            float wc = __expf(pc - m), wd = __expf(pd - m);
            s += (wa + wb) + (wc + wd);
            fast_update<NW>(wa, a0, acc);
            fast_update<NW>(wb, a1, acc);
            fast_update<NW>(wc, a2, acc);
            fast_update<NW>(wd, a3, acc);
        }
    }

    float inv = 1.f / s;
    f2 inv2 = {inv, inv};
    float val[F];
#pragma unroll
    for (int i = 0; i < NW; i++) {
        f2 xrf = __builtin_convertvector(xrh[i], f2);
        f2 v = __builtin_elementwise_fma(acc[i], inv2, -xrf);   // acc/s - xr
        val[2 * i] = v.x; val[2 * i + 1] = v.y;
    }
#pragma unroll
    for (int i = 0; i < F; i++) {                 // sum the 4 heads
        val[i] += __shfl_xor(val[i], 16, 64);
        val[i] += __shfl_xor(val[i], 32, 64);
    }
    if (lane < 16) {
        if (OUT == 0) {
            unsigned short h[F], lo[F];
#pragma unroll
            for (int i = 0; i < F; i++) {
                float v = fmaf(val[i], 0.25f, bias[lane * F + i]);
                v = fmaxf(v, 0.f);
                h[i] = f2bf(v);
                lo[i] = f2bf(v - bf2f(h[i]));
            }
            size_t base = (size_t)wv * (16 * F) + lane * F;
#pragma unroll
            for (int i = 0; i < F / 2; i++) {
                ((unsigned*)(Yhi + base))[i] = (unsigned)h[2 * i] | ((unsigned)h[2 * i + 1] << 16);
                ((unsigned*)(Ylo + base))[i] = (unsigned)lo[2 * i] | ((unsigned)lo[2 * i + 1] << 16);
            }
        } else {
            float* op = out + (size_t)wv * (16 * F) + lane * F;
#pragma unroll
            for (int i = 0; i < F; i++)
                op[i] = fmaf(val[i], 0.25f, bias[lane * F + i]);
        }
    }
}

// ---------------------------------------------------------------------------

static inline size_t align256(size_t x) { return (x + 255) & ~(size_t)255; }

extern "C" void kernel_launch(void* const* d_in, const int* in_sizes, int n_in,
                              void* d_out, int out_size, void* d_ws, size_t ws_size,
                              hipStream_t stream) {
    const float* x  = (const float*)d_in[0];
    const int*   ei = (const int*)d_in[1];
    const int N  = in_sizes[0] / 9;
    const int E  = in_sizes[1] / 2;
    const int EP = E + N;
    const int* src = ei;
    const int* dst = ei + E;

    const float *Wl[3], *bl[3], *Wr[3], *br[3], *att[3], *bb[3];
    for (int i = 0; i < 3; i++) {
        Wl[i]  = (const float*)d_in[2 + 6 * i];
        bl[i]  = (const float*)d_in[3 + 6 * i];
        Wr[i]  = (const float*)d_in[4 + 6 * i];
        br[i]  = (const float*)d_in[5 + 6 * i];
        att[i] = (const float*)d_in[6 + 6 * i];
        bb[i]  = (const float*)d_in[7 + 6 * i];
    }

    // workspace layout (~131 MB)
    char* w = (char*)d_ws;
    unsigned short* xl  = (unsigned short*)w; w += align256((size_t)N * 512 * 2);
    unsigned short* xr  = (unsigned short*)w; w += align256((size_t)N * 512 * 2);
    unsigned short* A1h = (unsigned short*)w; w += align256((size_t)N * 64 * 2);
    unsigned short* A1l = (unsigned short*)w; w += align256((size_t)N * 64 * 2);
    unsigned short* A2h = (unsigned short*)w; w += align256((size_t)N * 64 * 2);
    unsigned short* A2l = (unsigned short*)w; w += align256((size_t)N * 64 * 2);
    int* offs   = (int*)w;  w += align256((size_t)(N + 1) * 4);
    int* cnt    = (int*)w;  w += align256((size_t)(2 * N) * 4);   // cnt + cnt2
    int* csrc   = (int*)w;  w += align256((size_t)EP * 4);
    int* partial = (int*)w; w += 4096;
    unsigned short* Wp1h = (unsigned short*)w; w += align256((size_t)32 * 1024 * 2);
    unsigned short* Wp1l = (unsigned short*)w; w += align256((size_t)32 * 1024 * 2);
    unsigned short* Wp2h = (unsigned short*)w; w += align256((size_t)64 * 1024 * 2);
    unsigned short* Wp2l = (unsigned short*)w; w += align256((size_t)64 * 1024 * 2);
    int* cnt2 = cnt + N;

    // ---- CSR build over dst (5 dispatches) ----
    zero_int_k<<<(2 * N + 255) / 256, 256, 0, stream>>>(cnt, 2 * N);
    count_k<<<(EP + 255) / 256, 256, 0, stream>>>(dst, cnt, E, EP);
    int nb = (N + 1023) / 1024;
    scan1_k<<<nb, 1024, 0, stream>>>(cnt, offs, partial, N);
    scan23_k<<<nb, 1024, 0, stream>>>(offs, partial, N);
    fill2_k<<<(EP + 255) / 256, 256, 0, stream>>>(src, dst, offs, cnt2, csrc, E, EP);

    // ---- pack L1/L2 weights (one dispatch) ----
    split_w2_k<<<(96 * 1024) / 256, 256, 0, stream>>>(
        Wl[1], Wr[1], Wp1h, Wp1l, Wl[2], Wr[2], Wp2h, Wp2l);

    const int nodeBlocks = (N + 3) / 4;
    const int gemmBlocks = (N + 63) / 64;

    // ---- layer 0: vector gemm + node pass -> A1 hi/lo split ----
    dim3 g1((N + 15) / 16, 1);
    gemm2_f16_k<9><<<g1, 256, 0, stream>>>(
        x, Wl[0], bl[0], Wr[0], br[0], xl, xr, N, 256);
    node_fused_k<4, 0><<<nodeBlocks, 256, 0, stream>>>(
        xl, xr, att[0], bb[0], offs, csrc, A1h, A1l, nullptr, N);

    // ---- layer 1: MFMA gemm + node pass -> A2 hi/lo split ----
    mfma_gemm_k<4><<<gemmBlocks, 256, 0, stream>>>(
        A1h, A1l, Wp1h, Wp1l, bl[1], br[1], xl, xr, N, 256);
    node_fused_k<4, 0><<<nodeBlocks, 256, 0, stream>>>(
        xl, xr, att[1], bb[1], offs, csrc, A2h, A2l, nullptr, N);

    // ---- layer 2: MFMA gemm + node pass -> fp32 d_out ----
    mfma_gemm_k<8><<<gemmBlocks, 256, 0, stream>>>(
        A2h, A2l, Wp2h, Wp2l, bl[2], br[2], xl, xr, N, 512);
    node_fused_k<8, 1><<<nodeBlocks, 256, 0, stream>>>(
        xl, xr, att[2], bb[2], offs, csrc, nullptr, nullptr, (float*)d_out, N);
}

// Round 15
// 394.923 us; speedup vs baseline: 1.0065x; 1.0065x over previous
//
#include <hip/hip_runtime.h>
#include <hip/hip_bf16.h>

// ---------------------------------------------------------------------------
// MultiHopGATv2, fused formulation v12b (v12 with exp2f spelling fix).
//   Hybrid node pass: F=4 (L0/L1) uses 4-edge iterations (light registers),
//   F=8 (L2) uses 2-edge iterations (r13: quad@F=8 collapses occupancy).
//   Logits in base-2 log domain (att pre-scaled by log2e) -> exp2f (native
//   v_exp_f32) saves one VALU per softmax weight. fp16 xl/xr, dot2 logits.
//   L1/L2 GEMMs: split-precision bf16 MFMA. CSR: 5 dispatches.
// ---------------------------------------------------------------------------

typedef __attribute__((ext_vector_type(8))) short bf16x8;
typedef __attribute__((ext_vector_type(4))) float f32x4;
typedef _Float16 f16;
typedef __attribute__((ext_vector_type(2))) _Float16 h2;
typedef __attribute__((ext_vector_type(2))) float f2;

#define LOG2E 1.44269504088896f

__device__ __forceinline__ unsigned short f2bf(float v) {
    unsigned u = __float_as_uint(v);
    u = (u + 0x7fff + ((u >> 16) & 1)) >> 16;   // round-to-nearest-even
    return (unsigned short)u;
}
__device__ __forceinline__ float bf2f(unsigned short h) {
    return __uint_as_float((unsigned)h << 16);
}

// ---------------- CSR build ----------------

__global__ void zero_int_k(int* p, int n) {
    int i = blockIdx.x * 256 + threadIdx.x;
    if (i < n) p[i] = 0;
}

__global__ void count_k(const int* __restrict__ dst, int* __restrict__ cnt,
                        int E, int EP) {
    int e = blockIdx.x * 256 + threadIdx.x;
    if (e >= EP) return;
    int d = (e < E) ? dst[e] : (e - E);
    atomicAdd(&cnt[d], 1);
}

__global__ void scan1_k(const int* __restrict__ cnt, int* __restrict__ offs,
                        int* __restrict__ partial, int N) {
    __shared__ int buf[2][1024];
    int g = blockIdx.x * 1024 + threadIdx.x;
    int v = (g < N) ? cnt[g] : 0;
    int pi = 0;
    buf[0][threadIdx.x] = v;
    __syncthreads();
    for (int s = 1; s < 1024; s <<= 1) {
        int t = buf[pi][threadIdx.x];
        if ((int)threadIdx.x >= s) t += buf[pi][threadIdx.x - s];
        buf[pi ^ 1][threadIdx.x] = t;
        pi ^= 1;
        __syncthreads();
    }
    int incl = buf[pi][threadIdx.x];
    if (g < N) offs[g + 1] = incl;
    if (threadIdx.x == 1023) partial[blockIdx.x] = incl;
}

__global__ void scan23_k(int* __restrict__ offs, const int* __restrict__ partial, int N) {
    __shared__ int preS;
    int b = blockIdx.x;
    if (threadIdx.x < 64) {
        int t = threadIdx.x;
        int v = (t < b) ? partial[t] : 0;
#pragma unroll
        for (int o = 32; o > 0; o >>= 1) v += __shfl_xor(v, o, 64);
        if (t == 0) preS = v;
    }
    __syncthreads();
    int pre = preS;
    int g = b * 1024 + threadIdx.x;
    if (g < N) offs[g + 1] += pre;
    if (g == 0) offs[0] = 0;
}

__global__ void fill2_k(const int* __restrict__ src, const int* __restrict__ dst,
                        const int* __restrict__ offs, int* __restrict__ cnt2,
                        int* __restrict__ csrc, int E, int EP) {
    int e = blockIdx.x * 256 + threadIdx.x;
    if (e >= EP) return;
    int sv, d;
    if (e < E) { sv = src[e]; d = dst[e]; }
    else       { sv = e - E;  d = sv; }
    int p = offs[d] + atomicAdd(&cnt2[d], 1);
    csrc[p] = sv;
}

// ---------------- L0 vector gemm (FIN=9), fp16 out ----------------
template <int FIN>
__global__ void gemm2_f16_k(const float* __restrict__ X,
                            const float* __restrict__ Wl, const float* __restrict__ bl,
                            const float* __restrict__ Wr, const float* __restrict__ br,
                            unsigned short* __restrict__ xl, unsigned short* __restrict__ xr,
                            int N, int HCT) {
    constexpr int RPT = 16;
    __shared__ float Xs[RPT][FIN];
    int tid  = threadIdx.x;
    int col  = blockIdx.y * 256 + tid;
    int row0 = blockIdx.x * RPT;
    for (int i = tid; i < RPT * FIN; i += 256) {
        int r = i / FIN, k = i % FIN;
        int gr = row0 + r;
        Xs[r][k] = (gr < N) ? X[(size_t)gr * FIN + k] : 0.f;
    }
    __syncthreads();
    float aL[RPT], aR[RPT];
    float b1 = bl[col], b2 = br[col];
#pragma unroll
    for (int r = 0; r < RPT; r++) { aL[r] = b1; aR[r] = b2; }
    for (int k = 0; k < FIN; k++) {
        float wl = Wl[(size_t)k * HCT + col];
        float wr = Wr[(size_t)k * HCT + col];
#pragma unroll
        for (int r = 0; r < RPT; r++) {
            float xv = Xs[r][k];
            aL[r] = fmaf(xv, wl, aL[r]);
            aR[r] = fmaf(xv, wr, aR[r]);
        }
    }
#pragma unroll
    for (int r = 0; r < RPT; r++) {
        int gr = row0 + r;
        if (gr < N) {
            xl[(size_t)gr * HCT + col] = __builtin_bit_cast(unsigned short, (f16)aL[r]);
            xr[(size_t)gr * HCT + col] = __builtin_bit_cast(unsigned short, (f16)aR[r]);
        }
    }
}

// ---------------- pack W (L1 and L2) into MFMA B-frag order, hi/lo ----------
__device__ __forceinline__ void pack_one(const float* Wl, const float* Wr,
                                         unsigned short* Wh, unsigned short* Wlo,
                                         int HCT, int t) {
    int j  = t & 7;
    int l  = (t >> 3) & 63;
    int ks = (t >> 9) & 1;
    int ct = t >> 10;
    int k  = ks * 32 + (l >> 4) * 8 + j;
    int cg = ct * 16 + (l & 15);
    float v = (cg < HCT) ? Wl[(size_t)k * HCT + cg] : Wr[(size_t)k * HCT + (cg - HCT)];
    unsigned short hi = f2bf(v);
    Wh[t]  = hi;
    Wlo[t] = f2bf(v - bf2f(hi));
}

__global__ void split_w2_k(const float* __restrict__ Wl1, const float* __restrict__ Wr1,
                           unsigned short* __restrict__ W1h, unsigned short* __restrict__ W1l,
                           const float* __restrict__ Wl2, const float* __restrict__ Wr2,
                           unsigned short* __restrict__ W2h, unsigned short* __restrict__ W2l) {
    int tid = blockIdx.x * 256 + threadIdx.x;
    if (tid < 32 * 1024) pack_one(Wl1, Wr1, W1h, W1l, 256, tid);
    else                 pack_one(Wl2, Wr2, W2h, W2l, 512, tid - 32 * 1024);
}

// ---------------- MFMA gemm: [N x 64] @ [64 x HCT] x2 -> fp16 ----------------
template <int CHUNKS>
__global__ void mfma_gemm_k(const unsigned short* __restrict__ Ahi,
                            const unsigned short* __restrict__ Alo,
                            const unsigned short* __restrict__ Wphi,
                            const unsigned short* __restrict__ Wplo,
                            const float* __restrict__ bl, const float* __restrict__ br,
                            unsigned short* __restrict__ xl, unsigned short* __restrict__ xr,
                            int N, int HCT) {
    __shared__ float lds[4][16][128];
    int tid = threadIdx.x;
    int w   = tid >> 6, l = tid & 63;
    int l15 = l & 15,  seg = l >> 4;
    int row  = blockIdx.x * 64 + w * 16 + l15;
    int arow = (row < N) ? row : (N - 1);

    bf16x8 a0h = *(const bf16x8*)(Ahi + (size_t)arow * 64 + seg * 8);
    bf16x8 a1h = *(const bf16x8*)(Ahi + (size_t)arow * 64 + 32 + seg * 8);
    bf16x8 a0l = *(const bf16x8*)(Alo + (size_t)arow * 64 + seg * 8);
    bf16x8 a1l = *(const bf16x8*)(Alo + (size_t)arow * 64 + 32 + seg * 8);

    for (int c = 0; c < CHUNKS; c++) {
        int mat   = (c * 128) / HCT;
        int mcol0 = (c * 128) % HCT;
        const float* bias = mat ? br : bl;
        unsigned short* out = mat ? xr : xl;
        f32x4 acc[8];
#pragma unroll
        for (int t = 0; t < 8; t++) {
            float bv = bias[mcol0 + t * 16 + l15];
            acc[t] = (f32x4){bv, bv, bv, bv};
        }
#pragma unroll
        for (int t = 0; t < 8; t++) {
            size_t ct = (size_t)(c * 8 + t);
            bf16x8 b0h = *(const bf16x8*)(Wphi + ((ct * 2    ) * 64 + l) * 8);
            bf16x8 b1h = *(const bf16x8*)(Wphi + ((ct * 2 + 1) * 64 + l) * 8);
            bf16x8 b0l = *(const bf16x8*)(Wplo + ((ct * 2    ) * 64 + l) * 8);
            bf16x8 b1l = *(const bf16x8*)(Wplo + ((ct * 2 + 1) * 64 + l) * 8);
            acc[t] = __builtin_amdgcn_mfma_f32_16x16x32_bf16(a0h, b0h, acc[t], 0, 0, 0);
            acc[t] = __builtin_amdgcn_mfma_f32_16x16x32_bf16(a1h, b1h, acc[t], 0, 0, 0);
            acc[t] = __builtin_amdgcn_mfma_f32_16x16x32_bf16(a0l, b0h, acc[t], 0, 0, 0);
            acc[t] = __builtin_amdgcn_mfma_f32_16x16x32_bf16(a1l, b1h, acc[t], 0, 0, 0);
            acc[t] = __builtin_amdgcn_mfma_f32_16x16x32_bf16(a0h, b0l, acc[t], 0, 0, 0);
            acc[t] = __builtin_amdgcn_mfma_f32_16x16x32_bf16(a1h, b1l, acc[t], 0, 0, 0);
        }
#pragma unroll
        for (int t = 0; t < 8; t++)
#pragma unroll
            for (int r = 0; r < 4; r++)
                lds[w][seg * 4 + r][t * 16 + l15] = acc[t][r];
#pragma unroll
        for (int r = 0; r < 16; r++) {
            int orow = blockIdx.x * 64 + w * 16 + r;
            if (orow < N) {
                float v0 = lds[w][r][2 * l];
                float v1 = lds[w][r][2 * l + 1];
                h2 hv = { (f16)v0, (f16)v1 };
                *(unsigned*)(out + (size_t)orow * HCT + mcol0 + 2 * l) =
                    __builtin_bit_cast(unsigned, hv);
            }
        }
    }
}

// ---------------- node pass helpers (base-2 log domain) ----------------

template <int NW>
__device__ __forceinline__ float edge_logit(const unsigned* rr, const h2* xrh,
                                            const h2* ath, h2* a) {
    float p1 = 0.f, p2 = 0.f;
#pragma unroll
    for (int i = 0; i < NW; i++) {
        h2 xv = __builtin_bit_cast(h2, rr[i]);
        a[i] = xv + xrh[i];
        unsigned au = __builtin_bit_cast(unsigned, a[i]) & 0x7FFF7FFFu;
        p1 = __builtin_amdgcn_fdot2(ath[i], a[i], p1, false);
        p2 = __builtin_amdgcn_fdot2(ath[i], __builtin_bit_cast(h2, au), p2, false);
    }
    return fmaf(0.6f, p1, 0.4f * p2);
}

__device__ __forceinline__ float head_reduce(float p) {
    p += __shfl_xor(p, 1, 64);
    p += __shfl_xor(p, 2, 64);
    p += __shfl_xor(p, 4, 64);
    p += __shfl_xor(p, 8, 64);
    return p;
}

template <int NW>
__device__ __forceinline__ void exact_update(float p, const h2* a,
                                             float& m, float& s, f2* acc) {
    float nm = fmaxf(m, p);
    float r  = exp2f(m - nm);
    float w  = exp2f(p - nm);
    s = fmaf(s, r, w);
    f2 r2 = {r, r}, w2 = {w, w};
#pragma unroll
    for (int i = 0; i < NW; i++) {
        f2 af = __builtin_convertvector(a[i], f2);
        acc[i] = __builtin_elementwise_fma(acc[i], r2, af * w2);
    }
    m = nm;
}

template <int NW>
__device__ __forceinline__ void fast_update(float w, const h2* a, f2* acc) {
    f2 w2 = {w, w};
#pragma unroll
    for (int i = 0; i < NW; i++) {
        f2 af = __builtin_convertvector(a[i], f2);
        acc[i] = __builtin_elementwise_fma(af, w2, acc[i]);
    }
}

// ---------------- fused node pass ----------------
// QUAD=true: 4 edges/iter (F=4 only, light registers); false: 2 edges/iter.
// OUT=0: write relu(res) as hi/lo bf16 split; OUT=1: fp32 out (no relu).
// acc accumulates w*a (a = xv+xr); epilogue: out = acc/s - xr per head.
template <int F, int OUT, bool QUAD>
__global__ void node_fused_k(const unsigned short* __restrict__ xl,
                             const unsigned short* __restrict__ xr,
                             const float* __restrict__ att, const float* __restrict__ bias,
                             const int* __restrict__ offs, const int* __restrict__ csrc,
                             unsigned short* __restrict__ Yhi, unsigned short* __restrict__ Ylo,
                             float* __restrict__ out, int N) {
    constexpr int HCT = 64 * F;
    constexpr int NW  = F / 2;
    int wv   = blockIdx.x * 4 + (threadIdx.x >> 6);
    int lane = threadIdx.x & 63;
    if (wv >= N) return;

    h2 xrh[NW], ath[NW];
    {
        const unsigned* xp = (const unsigned*)(xr + (size_t)wv * HCT + lane * F);
#pragma unroll
        for (int i = 0; i < NW; i++) {
            xrh[i] = __builtin_bit_cast(h2, xp[i]);
            // att pre-scaled by log2(e): logits live in base-2 log domain.
            ath[i] = h2{ (f16)(LOG2E * att[lane * F + 2 * i]),
                         (f16)(LOG2E * att[lane * F + 2 * i + 1]) };
        }
    }

    int o0 = offs[wv], o1 = offs[wv + 1];
    int deg = o1 - o0;
    float m = -1e30f, s = 0.f;
    f2 acc[NW];
#pragma unroll
    for (int i = 0; i < NW; i++) acc[i] = f2{0.f, 0.f};

    int j = o0;
    if (deg & 1) {                          // single (exact) — also inits m
        const unsigned* xp = (const unsigned*)(xl + (size_t)csrc[j] * HCT + lane * F);
        unsigned rr[NW];
#pragma unroll
        for (int i = 0; i < NW; i++) rr[i] = xp[i];
        h2 a[NW];
        float p = head_reduce(edge_logit<NW>(rr, xrh, ath, a));
        exact_update<NW>(p, a, m, s, acc);
        j++;
    }
    if (QUAD && (deg & 2)) {                // pair step (quad variant only)
        const unsigned* xp0 = (const unsigned*)(xl + (size_t)csrc[j]     * HCT + lane * F);
        const unsigned* xp1 = (const unsigned*)(xl + (size_t)csrc[j + 1] * HCT + lane * F);
        unsigned r0[NW], r1[NW];
#pragma unroll
        for (int i = 0; i < NW; i++) r0[i] = xp0[i];
#pragma unroll
        for (int i = 0; i < NW; i++) r1[i] = xp1[i];
        h2 a0[NW], a1[NW];
        float pa = edge_logit<NW>(r0, xrh, ath, a0);
        float pb = edge_logit<NW>(r1, xrh, ath, a1);
        pa = head_reduce(pa);
        pb = head_reduce(pb);
        if (__any(fmaxf(pa, pb) > m + 20.f)) {
            exact_update<NW>(pa, a0, m, s, acc);
            exact_update<NW>(pb, a1, m, s, acc);
        } else {
            float wa = exp2f(pa - m), wb = exp2f(pb - m);
            s += wa + wb;
            fast_update<NW>(wa, a0, acc);
            fast_update<NW>(wb, a1, acc);
        }
        j += 2;
    }

    if (QUAD) {
        for (; j < o1; j += 4) {            // quad loop: 4 gathers in flight
            const unsigned* xp0 = (const unsigned*)(xl + (size_t)csrc[j]     * HCT + lane * F);
            const unsigned* xp1 = (const unsigned*)(xl + (size_t)csrc[j + 1] * HCT + lane * F);
            const unsigned* xp2 = (const unsigned*)(xl + (size_t)csrc[j + 2] * HCT + lane * F);
            const unsigned* xp3 = (const unsigned*)(xl + (size_t)csrc[j + 3] * HCT + lane * F);
            unsigned r0[NW], r1[NW], r2[NW], r3[NW];
#pragma unroll
            for (int i = 0; i < NW; i++) r0[i] = xp0[i];
#pragma unroll
            for (int i = 0; i < NW; i++) r1[i] = xp1[i];
#pragma unroll
            for (int i = 0; i < NW; i++) r2[i] = xp2[i];
#pragma unroll
            for (int i = 0; i < NW; i++) r3[i] = xp3[i];
            h2 a0[NW], a1[NW], a2[NW], a3[NW];
            float pa = edge_logit<NW>(r0, xrh, ath, a0);
            float pb = edge_logit<NW>(r1, xrh, ath, a1);
            float pc = edge_logit<NW>(r2, xrh, ath, a2);
            float pd = edge_logit<NW>(r3, xrh, ath, a3);
            pa = head_reduce(pa);
            pb = head_reduce(pb);
            pc = head_reduce(pc);
            pd = head_reduce(pd);
            float pm = fmaxf(fmaxf(pa, pb), fmaxf(pc, pd));
            if (__any(pm > m + 20.f)) {
                exact_update<NW>(pa, a0, m, s, acc);
                exact_update<NW>(pb, a1, m, s, acc);
                exact_update<NW>(pc, a2, m, s, acc);
                exact_update<NW>(pd, a3, m, s, acc);
            } else {
                float wa = exp2f(pa - m), wb = exp2f(pb - m);
                float wc = exp2f(pc - m), wd = exp2f(pd - m);
                s += (wa + wb) + (wc + wd);
                fast_update<NW>(wa, a0, acc);
                fast_update<NW>(wb, a1, acc);
                fast_update<NW>(wc, a2, acc);
                fast_update<NW>(wd, a3, acc);
            }
        }
    } else {
        for (; j < o1; j += 2) {            // pair loop: 2 gathers in flight
            const unsigned* xp0 = (const unsigned*)(xl + (size_t)csrc[j]     * HCT + lane * F);
            const unsigned* xp1 = (const unsigned*)(xl + (size_t)csrc[j + 1] * HCT + lane * F);
            unsigned r0[NW], r1[NW];
#pragma unroll
            for (int i = 0; i < NW; i++) r0[i] = xp0[i];
#pragma unroll
            for (int i = 0; i < NW; i++) r1[i] = xp1[i];
            h2 a0[NW], a1[NW];
            float pa = edge_logit<NW>(r0, xrh, ath, a0);
            float pb = edge_logit<NW>(r1, xrh, ath, a1);
            pa = head_reduce(pa);
            pb = head_reduce(pb);
            if (__any(fmaxf(pa, pb) > m + 20.f)) {
                exact_update<NW>(pa, a0, m, s, acc);
                exact_update<NW>(pb, a1, m, s, acc);
            } else {
                float wa = exp2f(pa - m), wb = exp2f(pb - m);
                s += wa + wb;
                fast_update<NW>(wa, a0, acc);
                fast_update<NW>(wb, a1, acc);
            }
        }
    }

    float inv = 1.f / s;
    f2 inv2 = {inv, inv};
    float val[F];
#pragma unroll
    for (int i = 0; i < NW; i++) {
        f2 xrf = __builtin_convertvector(xrh[i], f2);
        f2 v = __builtin_elementwise_fma(acc[i], inv2, -xrf);   // acc/s - xr
        val[2 * i] = v.x; val[2 * i + 1] = v.y;
    }
#pragma unroll
    for (int i = 0; i < F; i++) {                 // sum the 4 heads
        val[i] += __shfl_xor(val[i], 16, 64);
        val[i] += __shfl_xor(val[i], 32, 64);
    }
    if (lane < 16) {
        if (OUT == 0) {
            unsigned short h[F], lo[F];
#pragma unroll
            for (int i = 0; i < F; i++) {
                float v = fmaf(val[i], 0.25f, bias[lane * F + i]);
                v = fmaxf(v, 0.f);
                h[i] = f2bf(v);
                lo[i] = f2bf(v - bf2f(h[i]));
            }
            size_t base = (size_t)wv * (16 * F) + lane * F;
#pragma unroll
            for (int i = 0; i < F / 2; i++) {
                ((unsigned*)(Yhi + base))[i] = (unsigned)h[2 * i] | ((unsigned)h[2 * i + 1] << 16);
                ((unsigned*)(Ylo + base))[i] = (unsigned)lo[2 * i] | ((unsigned)lo[2 * i + 1] << 16);
            }
        } else {
            float* op = out + (size_t)wv * (16 * F) + lane * F;
#pragma unroll
            for (int i = 0; i < F; i++)
                op[i] = fmaf(val[i], 0.25f, bias[lane * F + i]);
        }
    }
}

// ---------------------------------------------------------------------------

static inline size_t align256(size_t x) { return (x + 255) & ~(size_t)255; }

extern "C" void kernel_launch(void* const* d_in, const int* in_sizes, int n_in,
                              void* d_out, int out_size, void* d_ws, size_t ws_size,
                              hipStream_t stream) {
    const float* x  = (const float*)d_in[0];
    const int*   ei = (const int*)d_in[1];
    const int N  = in_sizes[0] / 9;
    const int E  = in_sizes[1] / 2;
    const int EP = E + N;
    const int* src = ei;
    const int* dst = ei + E;

    const float *Wl[3], *bl[3], *Wr[3], *br[3], *att[3], *bb[3];
    for (int i = 0; i < 3; i++) {
        Wl[i]  = (const float*)d_in[2 + 6 * i];
        bl[i]  = (const float*)d_in[3 + 6 * i];
        Wr[i]  = (const float*)d_in[4 + 6 * i];
        br[i]  = (const float*)d_in[5 + 6 * i];
        att[i] = (const float*)d_in[6 + 6 * i];
        bb[i]  = (const float*)d_in[7 + 6 * i];
    }

    // workspace layout (~131 MB)
    char* w = (char*)d_ws;
    unsigned short* xl  = (unsigned short*)w; w += align256((size_t)N * 512 * 2);
    unsigned short* xr  = (unsigned short*)w; w += align256((size_t)N * 512 * 2);
    unsigned short* A1h = (unsigned short*)w; w += align256((size_t)N * 64 * 2);
    unsigned short* A1l = (unsigned short*)w; w += align256((size_t)N * 64 * 2);
    unsigned short* A2h = (unsigned short*)w; w += align256((size_t)N * 64 * 2);
    unsigned short* A2l = (unsigned short*)w; w += align256((size_t)N * 64 * 2);
    int* offs   = (int*)w;  w += align256((size_t)(N + 1) * 4);
    int* cnt    = (int*)w;  w += align256((size_t)(2 * N) * 4);   // cnt + cnt2
    int* csrc   = (int*)w;  w += align256((size_t)EP * 4);
    int* partial = (int*)w; w += 4096;
    unsigned short* Wp1h = (unsigned short*)w; w += align256((size_t)32 * 1024 * 2);
    unsigned short* Wp1l = (unsigned short*)w; w += align256((size_t)32 * 1024 * 2);
    unsigned short* Wp2h = (unsigned short*)w; w += align256((size_t)64 * 1024 * 2);
    unsigned short* Wp2l = (unsigned short*)w; w += align256((size_t)64 * 1024 * 2);
    int* cnt2 = cnt + N;

    // ---- CSR build over dst (5 dispatches) ----
    zero_int_k<<<(2 * N + 255) / 256, 256, 0, stream>>>(cnt, 2 * N);
    count_k<<<(EP + 255) / 256, 256, 0, stream>>>(dst, cnt, E, EP);
    int nb = (N + 1023) / 1024;
    scan1_k<<<nb, 1024, 0, stream>>>(cnt, offs, partial, N);
    scan23_k<<<nb, 1024, 0, stream>>>(offs, partial, N);
    fill2_k<<<(EP + 255) / 256, 256, 0, stream>>>(src, dst, offs, cnt2, csrc, E, EP);

    // ---- pack L1/L2 weights (one dispatch) ----
    split_w2_k<<<(96 * 1024) / 256, 256, 0, stream>>>(
        Wl[1], Wr[1], Wp1h, Wp1l, Wl[2], Wr[2], Wp2h, Wp2l);

    const int nodeBlocks = (N + 3) / 4;
    const int gemmBlocks = (N + 63) / 64;

    // ---- layer 0: vector gemm + node pass (quad) -> A1 hi/lo split ----
    dim3 g1((N + 15) / 16, 1);
    gemm2_f16_k<9><<<g1, 256, 0, stream>>>(
        x, Wl[0], bl[0], Wr[0], br[0], xl, xr, N, 256);
    node_fused_k<4, 0, true><<<nodeBlocks, 256, 0, stream>>>(
        xl, xr, att[0], bb[0], offs, csrc, A1h, A1l, nullptr, N);

    // ---- layer 1: MFMA gemm + node pass (quad) -> A2 hi/lo split ----
    mfma_gemm_k<4><<<gemmBlocks, 256, 0, stream>>>(
        A1h, A1l, Wp1h, Wp1l, bl[1], br[1], xl, xr, N, 256);
    node_fused_k<4, 0, true><<<nodeBlocks, 256, 0, stream>>>(
        xl, xr, att[1], bb[1], offs, csrc, A2h, A2l, nullptr, N);

    // ---- layer 2: MFMA gemm + node pass (pair) -> fp32 d_out ----
    mfma_gemm_k<8><<<gemmBlocks, 256, 0, stream>>>(
        A2h, A2l, Wp2h, Wp2l, bl[2], br[2], xl, xr, N, 512);
    node_fused_k<8, 1, false><<<nodeBlocks, 256, 0, stream>>>(
        xl, xr, att[2], bb[2], offs, csrc, nullptr, nullptr, (float*)d_out, N);
}

// Round 16
// 390.525 us; speedup vs baseline: 1.0178x; 1.0113x over previous
//
#include <hip/hip_runtime.h>
#include <hip/hip_bf16.h>

// ---------------------------------------------------------------------------
// MultiHopGATv2, fused formulation v13.
//   v12b + (a) node passes use 128-thread blocks (2 waves) to halve
//   degree-tail block imbalance (deg ~ Poisson(11), block completes at
//   max of member waves); (b) cnt zeroing via hipMemsetAsync (one fewer
//   dispatch). Hybrid unroll: quad for F=4, pair for F=8. exp2f domain.
//   L1/L2 GEMMs: split-precision bf16 MFMA. CSR: 4 dispatches + memset.
// ---------------------------------------------------------------------------

typedef __attribute__((ext_vector_type(8))) short bf16x8;
typedef __attribute__((ext_vector_type(4))) float f32x4;
typedef _Float16 f16;
typedef __attribute__((ext_vector_type(2))) _Float16 h2;
typedef __attribute__((ext_vector_type(2))) float f2;

#define LOG2E 1.44269504088896f

__device__ __forceinline__ unsigned short f2bf(float v) {
    unsigned u = __float_as_uint(v);
    u = (u + 0x7fff + ((u >> 16) & 1)) >> 16;   // round-to-nearest-even
    return (unsigned short)u;
}
__device__ __forceinline__ float bf2f(unsigned short h) {
    return __uint_as_float((unsigned)h << 16);
}

// ---------------- CSR build ----------------

__global__ void count_k(const int* __restrict__ dst, int* __restrict__ cnt,
                        int E, int EP) {
    int e = blockIdx.x * 256 + threadIdx.x;
    if (e >= EP) return;
    int d = (e < E) ? dst[e] : (e - E);
    atomicAdd(&cnt[d], 1);
}

__global__ void scan1_k(const int* __restrict__ cnt, int* __restrict__ offs,
                        int* __restrict__ partial, int N) {
    __shared__ int buf[2][1024];
    int g = blockIdx.x * 1024 + threadIdx.x;
    int v = (g < N) ? cnt[g] : 0;
    int pi = 0;
    buf[0][threadIdx.x] = v;
    __syncthreads();
    for (int s = 1; s < 1024; s <<= 1) {
        int t = buf[pi][threadIdx.x];
        if ((int)threadIdx.x >= s) t += buf[pi][threadIdx.x - s];
        buf[pi ^ 1][threadIdx.x] = t;
        pi ^= 1;
        __syncthreads();
    }
    int incl = buf[pi][threadIdx.x];
    if (g < N) offs[g + 1] = incl;
    if (threadIdx.x == 1023) partial[blockIdx.x] = incl;
}

__global__ void scan23_k(int* __restrict__ offs, const int* __restrict__ partial, int N) {
    __shared__ int preS;
    int b = blockIdx.x;
    if (threadIdx.x < 64) {
        int t = threadIdx.x;
        int v = (t < b) ? partial[t] : 0;
#pragma unroll
        for (int o = 32; o > 0; o >>= 1) v += __shfl_xor(v, o, 64);
        if (t == 0) preS = v;
    }
    __syncthreads();
    int pre = preS;
    int g = b * 1024 + threadIdx.x;
    if (g < N) offs[g + 1] += pre;
    if (g == 0) offs[0] = 0;
}

__global__ void fill2_k(const int* __restrict__ src, const int* __restrict__ dst,
                        const int* __restrict__ offs, int* __restrict__ cnt2,
                        int* __restrict__ csrc, int E, int EP) {
    int e = blockIdx.x * 256 + threadIdx.x;
    if (e >= EP) return;
    int sv, d;
    if (e < E) { sv = src[e]; d = dst[e]; }
    else       { sv = e - E;  d = sv; }
    int p = offs[d] + atomicAdd(&cnt2[d], 1);
    csrc[p] = sv;
}

// ---------------- L0 vector gemm (FIN=9), fp16 out ----------------
template <int FIN>
__global__ void gemm2_f16_k(const float* __restrict__ X,
                            const float* __restrict__ Wl, const float* __restrict__ bl,
                            const float* __restrict__ Wr, const float* __restrict__ br,
                            unsigned short* __restrict__ xl, unsigned short* __restrict__ xr,
                            int N, int HCT) {
    constexpr int RPT = 16;
    __shared__ float Xs[RPT][FIN];
    int tid  = threadIdx.x;
    int col  = blockIdx.y * 256 + tid;
    int row0 = blockIdx.x * RPT;
    for (int i = tid; i < RPT * FIN; i += 256) {
        int r = i / FIN, k = i % FIN;
        int gr = row0 + r;
        Xs[r][k] = (gr < N) ? X[(size_t)gr * FIN + k] : 0.f;
    }
    __syncthreads();
    float aL[RPT], aR[RPT];
    float b1 = bl[col], b2 = br[col];
#pragma unroll
    for (int r = 0; r < RPT; r++) { aL[r] = b1; aR[r] = b2; }
    for (int k = 0; k < FIN; k++) {
        float wl = Wl[(size_t)k * HCT + col];
        float wr = Wr[(size_t)k * HCT + col];
#pragma unroll
        for (int r = 0; r < RPT; r++) {
            float xv = Xs[r][k];
            aL[r] = fmaf(xv, wl, aL[r]);
            aR[r] = fmaf(xv, wr, aR[r]);
        }
    }
#pragma unroll
    for (int r = 0; r < RPT; r++) {
        int gr = row0 + r;
        if (gr < N) {
            xl[(size_t)gr * HCT + col] = __builtin_bit_cast(unsigned short, (f16)aL[r]);
            xr[(size_t)gr * HCT + col] = __builtin_bit_cast(unsigned short, (f16)aR[r]);
        }
    }
}

// ---------------- pack W (L1 and L2) into MFMA B-frag order, hi/lo ----------
__device__ __forceinline__ void pack_one(const float* Wl, const float* Wr,
                                         unsigned short* Wh, unsigned short* Wlo,
                                         int HCT, int t) {
    int j  = t & 7;
    int l  = (t >> 3) & 63;
    int ks = (t >> 9) & 1;
    int ct = t >> 10;
    int k  = ks * 32 + (l >> 4) * 8 + j;
    int cg = ct * 16 + (l & 15);
    float v = (cg < HCT) ? Wl[(size_t)k * HCT + cg] : Wr[(size_t)k * HCT + (cg - HCT)];
    unsigned short hi = f2bf(v);
    Wh[t]  = hi;
    Wlo[t] = f2bf(v - bf2f(hi));
}

__global__ void split_w2_k(const float* __restrict__ Wl1, const float* __restrict__ Wr1,
                           unsigned short* __restrict__ W1h, unsigned short* __restrict__ W1l,
                           const float* __restrict__ Wl2, const float* __restrict__ Wr2,
                           unsigned short* __restrict__ W2h, unsigned short* __restrict__ W2l) {
    int tid = blockIdx.x * 256 + threadIdx.x;
    if (tid < 32 * 1024) pack_one(Wl1, Wr1, W1h, W1l, 256, tid);
    else                 pack_one(Wl2, Wr2, W2h, W2l, 512, tid - 32 * 1024);
}

// ---------------- MFMA gemm: [N x 64] @ [64 x HCT] x2 -> fp16 ----------------
template <int CHUNKS>
__global__ void mfma_gemm_k(const unsigned short* __restrict__ Ahi,
                            const unsigned short* __restrict__ Alo,
                            const unsigned short* __restrict__ Wphi,
                            const unsigned short* __restrict__ Wplo,
                            const float* __restrict__ bl, const float* __restrict__ br,
                            unsigned short* __restrict__ xl, unsigned short* __restrict__ xr,
                            int N, int HCT) {
    __shared__ float lds[4][16][128];
    int tid = threadIdx.x;
    int w   = tid >> 6, l = tid & 63;
    int l15 = l & 15,  seg = l >> 4;
    int row  = blockIdx.x * 64 + w * 16 + l15;
    int arow = (row < N) ? row : (N - 1);

    bf16x8 a0h = *(const bf16x8*)(Ahi + (size_t)arow * 64 + seg * 8);
    bf16x8 a1h = *(const bf16x8*)(Ahi + (size_t)arow * 64 + 32 + seg * 8);
    bf16x8 a0l = *(const bf16x8*)(Alo + (size_t)arow * 64 + seg * 8);
    bf16x8 a1l = *(const bf16x8*)(Alo + (size_t)arow * 64 + 32 + seg * 8);

    for (int c = 0; c < CHUNKS; c++) {
        int mat   = (c * 128) / HCT;
        int mcol0 = (c * 128) % HCT;
        const float* bias = mat ? br : bl;
        unsigned short* out = mat ? xr : xl;
        f32x4 acc[8];
#pragma unroll
        for (int t = 0; t < 8; t++) {
            float bv = bias[mcol0 + t * 16 + l15];
            acc[t] = (f32x4){bv, bv, bv, bv};
        }
#pragma unroll
        for (int t = 0; t < 8; t++) {
            size_t ct = (size_t)(c * 8 + t);
            bf16x8 b0h = *(const bf16x8*)(Wphi + ((ct * 2    ) * 64 + l) * 8);
            bf16x8 b1h = *(const bf16x8*)(Wphi + ((ct * 2 + 1) * 64 + l) * 8);
            bf16x8 b0l = *(const bf16x8*)(Wplo + ((ct * 2    ) * 64 + l) * 8);
            bf16x8 b1l = *(const bf16x8*)(Wplo + ((ct * 2 + 1) * 64 + l) * 8);
            acc[t] = __builtin_amdgcn_mfma_f32_16x16x32_bf16(a0h, b0h, acc[t], 0, 0, 0);
            acc[t] = __builtin_amdgcn_mfma_f32_16x16x32_bf16(a1h, b1h, acc[t], 0, 0, 0);
            acc[t] = __builtin_amdgcn_mfma_f32_16x16x32_bf16(a0l, b0h, acc[t], 0, 0, 0);
            acc[t] = __builtin_amdgcn_mfma_f32_16x16x32_bf16(a1l, b1h, acc[t], 0, 0, 0);
            acc[t] = __builtin_amdgcn_mfma_f32_16x16x32_bf16(a0h, b0l, acc[t], 0, 0, 0);
            acc[t] = __builtin_amdgcn_mfma_f32_16x16x32_bf16(a1h, b1l, acc[t], 0, 0, 0);
        }
#pragma unroll
        for (int t = 0; t < 8; t++)
#pragma unroll
            for (int r = 0; r < 4; r++)
                lds[w][seg * 4 + r][t * 16 + l15] = acc[t][r];
#pragma unroll
        for (int r = 0; r < 16; r++) {
            int orow = blockIdx.x * 64 + w * 16 + r;
            if (orow < N) {
                float v0 = lds[w][r][2 * l];
                float v1 = lds[w][r][2 * l + 1];
                h2 hv = { (f16)v0, (f16)v1 };
                *(unsigned*)(out + (size_t)orow * HCT + mcol0 + 2 * l) =
                    __builtin_bit_cast(unsigned, hv);
            }
        }
    }
}

// ---------------- node pass helpers (base-2 log domain) ----------------

template <int NW>
__device__ __forceinline__ float edge_logit(const unsigned* rr, const h2* xrh,
                                            const h2* ath, h2* a) {
    float p1 = 0.f, p2 = 0.f;
#pragma unroll
    for (int i = 0; i < NW; i++) {
        h2 xv = __builtin_bit_cast(h2, rr[i]);
        a[i] = xv + xrh[i];
        unsigned au = __builtin_bit_cast(unsigned, a[i]) & 0x7FFF7FFFu;
        p1 = __builtin_amdgcn_fdot2(ath[i], a[i], p1, false);
        p2 = __builtin_amdgcn_fdot2(ath[i], __builtin_bit_cast(h2, au), p2, false);
    }
    return fmaf(0.6f, p1, 0.4f * p2);
}

__device__ __forceinline__ float head_reduce(float p) {
    p += __shfl_xor(p, 1, 64);
    p += __shfl_xor(p, 2, 64);
    p += __shfl_xor(p, 4, 64);
    p += __shfl_xor(p, 8, 64);
    return p;
}

template <int NW>
__device__ __forceinline__ void exact_update(float p, const h2* a,
                                             float& m, float& s, f2* acc) {
    float nm = fmaxf(m, p);
    float r  = exp2f(m - nm);
    float w  = exp2f(p - nm);
    s = fmaf(s, r, w);
    f2 r2 = {r, r}, w2 = {w, w};
#pragma unroll
    for (int i = 0; i < NW; i++) {
        f2 af = __builtin_convertvector(a[i], f2);
        acc[i] = __builtin_elementwise_fma(acc[i], r2, af * w2);
    }
    m = nm;
}

template <int NW>
__device__ __forceinline__ void fast_update(float w, const h2* a, f2* acc) {
    f2 w2 = {w, w};
#pragma unroll
    for (int i = 0; i < NW; i++) {
        f2 af = __builtin_convertvector(a[i], f2);
        acc[i] = __builtin_elementwise_fma(af, w2, acc[i]);
    }
}

// ---------------- fused node pass (128-thread blocks = 2 waves) ----------------
// QUAD=true: 4 edges/iter (F=4, light registers); false: 2 edges/iter (F=8).
// OUT=0: write relu(res) as hi/lo bf16 split; OUT=1: fp32 out (no relu).
// acc accumulates w*a (a = xv+xr); epilogue: out = acc/s - xr per head.
template <int F, int OUT, bool QUAD>
__global__ void node_fused_k(const unsigned short* __restrict__ xl,
                             const unsigned short* __restrict__ xr,
                             const float* __restrict__ att, const float* __restrict__ bias,
                             const int* __restrict__ offs, const int* __restrict__ csrc,
                             unsigned short* __restrict__ Yhi, unsigned short* __restrict__ Ylo,
                             float* __restrict__ out, int N) {
    constexpr int HCT = 64 * F;
    constexpr int NW  = F / 2;
    int wv   = blockIdx.x * 2 + (threadIdx.x >> 6);
    int lane = threadIdx.x & 63;
    if (wv >= N) return;

    h2 xrh[NW], ath[NW];
    {
        const unsigned* xp = (const unsigned*)(xr + (size_t)wv * HCT + lane * F);
#pragma unroll
        for (int i = 0; i < NW; i++) {
            xrh[i] = __builtin_bit_cast(h2, xp[i]);
            // att pre-scaled by log2(e): logits live in base-2 log domain.
            ath[i] = h2{ (f16)(LOG2E * att[lane * F + 2 * i]),
                         (f16)(LOG2E * att[lane * F + 2 * i + 1]) };
        }
    }

    int o0 = offs[wv], o1 = offs[wv + 1];
    int deg = o1 - o0;
    float m = -1e30f, s = 0.f;
    f2 acc[NW];
#pragma unroll
    for (int i = 0; i < NW; i++) acc[i] = f2{0.f, 0.f};

    int j = o0;
    if (deg & 1) {                          // single (exact) — also inits m
        const unsigned* xp = (const unsigned*)(xl + (size_t)csrc[j] * HCT + lane * F);
        unsigned rr[NW];
#pragma unroll
        for (int i = 0; i < NW; i++) rr[i] = xp[i];
        h2 a[NW];
        float p = head_reduce(edge_logit<NW>(rr, xrh, ath, a));
        exact_update<NW>(p, a, m, s, acc);
        j++;
    }
    if (QUAD && (deg & 2)) {                // pair step (quad variant only)
        const unsigned* xp0 = (const unsigned*)(xl + (size_t)csrc[j]     * HCT + lane * F);
        const unsigned* xp1 = (const unsigned*)(xl + (size_t)csrc[j + 1] * HCT + lane * F);
        unsigned r0[NW], r1[NW];
#pragma unroll
        for (int i = 0; i < NW; i++) r0[i] = xp0[i];
#pragma unroll
        for (int i = 0; i < NW; i++) r1[i] = xp1[i];
        h2 a0[NW], a1[NW];
        float pa = edge_logit<NW>(r0, xrh, ath, a0);
        float pb = edge_logit<NW>(r1, xrh, ath, a1);
        pa = head_reduce(pa);
        pb = head_reduce(pb);
        if (__any(fmaxf(pa, pb) > m + 20.f)) {
            exact_update<NW>(pa, a0, m, s, acc);
            exact_update<NW>(pb, a1, m, s, acc);
        } else {
            float wa = exp2f(pa - m), wb = exp2f(pb - m);
            s += wa + wb;
            fast_update<NW>(wa, a0, acc);
            fast_update<NW>(wb, a1, acc);
        }
        j += 2;
    }

    if (QUAD) {
        for (; j < o1; j += 4) {            // quad loop: 4 gathers in flight
            const unsigned* xp0 = (const unsigned*)(xl + (size_t)csrc[j]     * HCT + lane * F);
            const unsigned* xp1 = (const unsigned*)(xl + (size_t)csrc[j + 1] * HCT + lane * F);
            const unsigned* xp2 = (const unsigned*)(xl + (size_t)csrc[j + 2] * HCT + lane * F);
            const unsigned* xp3 = (const unsigned*)(xl + (size_t)csrc[j + 3] * HCT + lane * F);
            unsigned r0[NW], r1[NW], r2[NW], r3[NW];
#pragma unroll
            for (int i = 0; i < NW; i++) r0[i] = xp0[i];
#pragma unroll
            for (int i = 0; i < NW; i++) r1[i] = xp1[i];
#pragma unroll
            for (int i = 0; i < NW; i++) r2[i] = xp2[i];
#pragma unroll
            for (int i = 0; i < NW; i++) r3[i] = xp3[i];
            h2 a0[NW], a1[NW], a2[NW], a3[NW];
            float pa = edge_logit<NW>(r0, xrh, ath, a0);
            float pb = edge_logit<NW>(r1, xrh, ath, a1);
            float pc = edge_logit<NW>(r2, xrh, ath, a2);
            float pd = edge_logit<NW>(r3, xrh, ath, a3);
            pa = head_reduce(pa);
            pb = head_reduce(pb);
            pc = head_reduce(pc);
            pd = head_reduce(pd);
            float pm = fmaxf(fmaxf(pa, pb), fmaxf(pc, pd));
            if (__any(pm > m + 20.f)) {
                exact_update<NW>(pa, a0, m, s, acc);
                exact_update<NW>(pb, a1, m, s, acc);
                exact_update<NW>(pc, a2, m, s, acc);
                exact_update<NW>(pd, a3, m, s, acc);
            } else {
                float wa = exp2f(pa - m), wb = exp2f(pb - m);
                float wc = exp2f(pc - m), wd = exp2f(pd - m);
                s += (wa + wb) + (wc + wd);
                fast_update<NW>(wa, a0, acc);
                fast_update<NW>(wb, a1, acc);
                fast_update<NW>(wc, a2, acc);
                fast_update<NW>(wd, a3, acc);
            }
        }
    } else {
        for (; j < o1; j += 2) {            // pair loop: 2 gathers in flight
            const unsigned* xp0 = (const unsigned*)(xl + (size_t)csrc[j]     * HCT + lane * F);
            const unsigned* xp1 = (const unsigned*)(xl + (size_t)csrc[j + 1] * HCT + lane * F);
            unsigned r0[NW], r1[NW];
#pragma unroll
            for (int i = 0; i < NW; i++) r0[i] = xp0[i];
#pragma unroll
            for (int i = 0; i < NW; i++) r1[i] = xp1[i];
            h2 a0[NW], a1[NW];
            float pa = edge_logit<NW>(r0, xrh, ath, a0);
            float pb = edge_logit<NW>(r1, xrh, ath, a1);
            pa = head_reduce(pa);
            pb = head_reduce(pb);
            if (__any(fmaxf(pa, pb) > m + 20.f)) {
                exact_update<NW>(pa, a0, m, s, acc);
                exact_update<NW>(pb, a1, m, s, acc);
            } else {
                float wa = exp2f(pa - m), wb = exp2f(pb - m);
                s += wa + wb;
                fast_update<NW>(wa, a0, acc);
                fast_update<NW>(wb, a1, acc);
            }
        }
    }

    float inv = 1.f / s;
    f2 inv2 = {inv, inv};
    float val[F];
#pragma unroll
    for (int i = 0; i < NW; i++) {
        f2 xrf = __builtin_convertvector(xrh[i], f2);
        f2 v = __builtin_elementwise_fma(acc[i], inv2, -xrf);   // acc/s - xr
        val[2 * i] = v.x; val[2 * i + 1] = v.y;
    }
#pragma unroll
    for (int i = 0; i < F; i++) {                 // sum the 4 heads
        val[i] += __shfl_xor(val[i], 16, 64);
        val[i] += __shfl_xor(val[i], 32, 64);
    }
    if (lane < 16) {
        if (OUT == 0) {
            unsigned short h[F], lo[F];
#pragma unroll
            for (int i = 0; i < F; i++) {
                float v = fmaf(val[i], 0.25f, bias[lane * F + i]);
                v = fmaxf(v, 0.f);
                h[i] = f2bf(v);
                lo[i] = f2bf(v - bf2f(h[i]));
            }
            size_t base = (size_t)wv * (16 * F) + lane * F;
#pragma unroll
            for (int i = 0; i < F / 2; i++) {
                ((unsigned*)(Yhi + base))[i] = (unsigned)h[2 * i] | ((unsigned)h[2 * i + 1] << 16);
                ((unsigned*)(Ylo + base))[i] = (unsigned)lo[2 * i] | ((unsigned)lo[2 * i + 1] << 16);
            }
        } else {
            float* op = out + (size_t)wv * (16 * F) + lane * F;
#pragma unroll
            for (int i = 0; i < F; i++)
                op[i] = fmaf(val[i], 0.25f, bias[lane * F + i]);
        }
    }
}

// ---------------------------------------------------------------------------

static inline size_t align256(size_t x) { return (x + 255) & ~(size_t)255; }

extern "C" void kernel_launch(void* const* d_in, const int* in_sizes, int n_in,
                              void* d_out, int out_size, void* d_ws, size_t ws_size,
                              hipStream_t stream) {
    const float* x  = (const float*)d_in[0];
    const int*   ei = (const int*)d_in[1];
    const int N  = in_sizes[0] / 9;
    const int E  = in_sizes[1] / 2;
    const int EP = E + N;
    const int* src = ei;
    const int* dst = ei + E;

    const float *Wl[3], *bl[3], *Wr[3], *br[3], *att[3], *bb[3];
    for (int i = 0; i < 3; i++) {
        Wl[i]  = (const float*)d_in[2 + 6 * i];
        bl[i]  = (const float*)d_in[3 + 6 * i];
        Wr[i]  = (const float*)d_in[4 + 6 * i];
        br[i]  = (const float*)d_in[5 + 6 * i];
        att[i] = (const float*)d_in[6 + 6 * i];
        bb[i]  = (const float*)d_in[7 + 6 * i];
    }

    // workspace layout (~131 MB)
    char* w = (char*)d_ws;
    unsigned short* xl  = (unsigned short*)w; w += align256((size_t)N * 512 * 2);
    unsigned short* xr  = (unsigned short*)w; w += align256((size_t)N * 512 * 2);
    unsigned short* A1h = (unsigned short*)w; w += align256((size_t)N * 64 * 2);
    unsigned short* A1l = (unsigned short*)w; w += align256((size_t)N * 64 * 2);
    unsigned short* A2h = (unsigned short*)w; w += align256((size_t)N * 64 * 2);
    unsigned short* A2l = (unsigned short*)w; w += align256((size_t)N * 64 * 2);
    int* offs   = (int*)w;  w += align256((size_t)(N + 1) * 4);
    int* cnt    = (int*)w;  w += align256((size_t)(2 * N) * 4);   // cnt + cnt2
    int* csrc   = (int*)w;  w += align256((size_t)EP * 4);
    int* partial = (int*)w; w += 4096;
    unsigned short* Wp1h = (unsigned short*)w; w += align256((size_t)32 * 1024 * 2);
    unsigned short* Wp1l = (unsigned short*)w; w += align256((size_t)32 * 1024 * 2);
    unsigned short* Wp2h = (unsigned short*)w; w += align256((size_t)64 * 1024 * 2);
    unsigned short* Wp2l = (unsigned short*)w; w += align256((size_t)64 * 1024 * 2);
    int* cnt2 = cnt + N;

    // ---- CSR build over dst (memset + 4 dispatches) ----
    hipMemsetAsync(cnt, 0, (size_t)(2 * N) * 4, stream);
    count_k<<<(EP + 255) / 256, 256, 0, stream>>>(dst, cnt, E, EP);
    int nb = (N + 1023) / 1024;
    scan1_k<<<nb, 1024, 0, stream>>>(cnt, offs, partial, N);
    scan23_k<<<nb, 1024, 0, stream>>>(offs, partial, N);
    fill2_k<<<(EP + 255) / 256, 256, 0, stream>>>(src, dst, offs, cnt2, csrc, E, EP);

    // ---- pack L1/L2 weights (one dispatch) ----
    split_w2_k<<<(96 * 1024) / 256, 256, 0, stream>>>(
        Wl[1], Wr[1], Wp1h, Wp1l, Wl[2], Wr[2], Wp2h, Wp2l);

    const int nodeBlocks = (N + 1) / 2;     // 128-thread blocks, 2 waves each
    const int gemmBlocks = (N + 63) / 64;

    // ---- layer 0: vector gemm + node pass (quad) -> A1 hi/lo split ----
    dim3 g1((N + 15) / 16, 1);
    gemm2_f16_k<9><<<g1, 256, 0, stream>>>(
        x, Wl[0], bl[0], Wr[0], br[0], xl, xr, N, 256);
    node_fused_k<4, 0, true><<<nodeBlocks, 128, 0, stream>>>(
        xl, xr, att[0], bb[0], offs, csrc, A1h, A1l, nullptr, N);

    // ---- layer 1: MFMA gemm + node pass (quad) -> A2 hi/lo split ----
    mfma_gemm_k<4><<<gemmBlocks, 256, 0, stream>>>(
        A1h, A1l, Wp1h, Wp1l, bl[1], br[1], xl, xr, N, 256);
    node_fused_k<4, 0, true><<<nodeBlocks, 128, 0, stream>>>(
        xl, xr, att[1], bb[1], offs, csrc, A2h, A2l, nullptr, N);

    // ---- layer 2: MFMA gemm + node pass (pair) -> fp32 d_out ----
    mfma_gemm_k<8><<<gemmBlocks, 256, 0, stream>>>(
        A2h, A2l, Wp2h, Wp2l, bl[2], br[2], xl, xr, N, 512);
    node_fused_k<8, 1, false><<<nodeBlocks, 128, 0, stream>>>(
        xl, xr, att[2], bb[2], offs, csrc, nullptr, nullptr, (float*)d_out, N);
}